// Round 3
// baseline (503.119 us; speedup 1.0000x reference)
//
#include <hip/hip_runtime.h>

// WelfordEstimator: sequential Welford over batch dim B=32, per (s,h) position.
// x: (32, 2048, 1024) fp32. State: (2048,1024) mean/m2 fp32, nonzero int32, n scalar int.
// Output layout (all read back as fp32 by harness):
//   [0, B*SH)          : x passthrough
//   [B*SH, B*SH+SH)    : mean
//   [+SH, +2SH)        : m2
//   [+2SH, +3SH)       : nonzero (as float value — counts <= 32+n0, exact in fp32)
//   [B*SH+3SH]         : num_samples (as float value)
//
// R3: burst-grouped R/W. Previous fine-grained [load,store] alternation per
// b-step gives 1 KB/direction bursts at DRAM; fills (write-only) hit 6.4 TB/s.
// Restructure into double-buffered groups of 8 batches: [8 NT loads (next
// group)] -> [8 compute steps (cur)] -> [8 NT stores (cur)], 8 KB/direction
// bursts per wave. Register sets are STATICALLY named (a0..a7 / b0..b7) —
// runtime-indexed arrays would go to scratch. Per-element FP expression
// sequence is IDENTICAL to the R2 version that passed.

#define BATCH 32
#define SH  (2048LL * 1024LL)   // 2,097,152 positions
#define SH4 (SH / 4)            // f32x4 stride between consecutive batches

typedef float f32x4 __attribute__((ext_vector_type(4)));
typedef int   i32x4 __attribute__((ext_vector_type(4)));

__global__ __launch_bounds__(256) void welford_kernel(
    const float* __restrict__ x,
    const float* __restrict__ mean_in,
    const float* __restrict__ m2_in,
    const int*   __restrict__ nz_in,
    const int*   __restrict__ n_in,
    float* __restrict__ out)
{
    const long long tid = (long long)blockIdx.x * blockDim.x + threadIdx.x;
    const long long pos = tid * 4;          // 4 consecutive positions per thread
    if (pos >= SH) return;

    const f32x4* __restrict__ xin  = (const f32x4*)(x + pos);
    f32x4*       __restrict__ xout = (f32x4*)(out + pos);

    f32x4 mean = *(const f32x4*)(mean_in + pos);
    f32x4 m2   = *(const f32x4*)(m2_in   + pos);
    i32x4 nz   = *(const i32x4*)(nz_in   + pos);
    const int n0 = *n_in;

    float* __restrict__ out_mean = out + (long long)BATCH * SH;
    float* __restrict__ out_m2   = out_mean + SH;
    float* __restrict__ out_nz   = out_m2 + SH;

#define NT_LD(b) __builtin_nontemporal_load(xin + (b) * SH4)
#define NT_ST(b, r) __builtin_nontemporal_store((r), xout + (b) * SH4)

    // One Welford compute step for one f32x4 (no store). Expression sequence
    // identical to the verified version: nz, d = x - old_mean, mean += d*inv,
    // m2 += (x - new_mean)*d. inv shared across the 4 lanes.
#define COMP(b, r)                                                             \
    {                                                                          \
        const float inv = 1.0f / (float)(n0 + (b) + 1);                        \
        nz[0] += ((r)[0] != 0.0f);                                             \
        { const float d = (r)[0] - mean[0]; mean[0] += d * inv;                \
          m2[0] += ((r)[0] - mean[0]) * d; }                                   \
        nz[1] += ((r)[1] != 0.0f);                                             \
        { const float d = (r)[1] - mean[1]; mean[1] += d * inv;                \
          m2[1] += ((r)[1] - mean[1]) * d; }                                   \
        nz[2] += ((r)[2] != 0.0f);                                             \
        { const float d = (r)[2] - mean[2]; mean[2] += d * inv;                \
          m2[2] += ((r)[2] - mean[2]) * d; }                                   \
        nz[3] += ((r)[3] != 0.0f);                                             \
        { const float d = (r)[3] - mean[3]; mean[3] += d * inv;                \
          m2[3] += ((r)[3] - mean[3]) * d; }                                   \
    }

    // ---- prologue: load group 0 (b = 0..7) into A set ----
    f32x4 a0 = NT_LD(0), a1 = NT_LD(1), a2 = NT_LD(2), a3 = NT_LD(3);
    f32x4 a4 = NT_LD(4), a5 = NT_LD(5), a6 = NT_LD(6), a7 = NT_LD(7);
    f32x4 b0, b1, b2, b3, b4, b5, b6, b7;

    // ---- epoch 0: prefetch group 1 into B; compute+store group 0 from A ----
    b0 = NT_LD(8);  b1 = NT_LD(9);  b2 = NT_LD(10); b3 = NT_LD(11);
    b4 = NT_LD(12); b5 = NT_LD(13); b6 = NT_LD(14); b7 = NT_LD(15);
    COMP(0, a0); COMP(1, a1); COMP(2, a2); COMP(3, a3);
    COMP(4, a4); COMP(5, a5); COMP(6, a6); COMP(7, a7);
    NT_ST(0, a0); NT_ST(1, a1); NT_ST(2, a2); NT_ST(3, a3);
    NT_ST(4, a4); NT_ST(5, a5); NT_ST(6, a6); NT_ST(7, a7);

    // ---- epoch 1: prefetch group 2 into A; compute+store group 1 from B ----
    a0 = NT_LD(16); a1 = NT_LD(17); a2 = NT_LD(18); a3 = NT_LD(19);
    a4 = NT_LD(20); a5 = NT_LD(21); a6 = NT_LD(22); a7 = NT_LD(23);
    COMP(8,  b0); COMP(9,  b1); COMP(10, b2); COMP(11, b3);
    COMP(12, b4); COMP(13, b5); COMP(14, b6); COMP(15, b7);
    NT_ST(8,  b0); NT_ST(9,  b1); NT_ST(10, b2); NT_ST(11, b3);
    NT_ST(12, b4); NT_ST(13, b5); NT_ST(14, b6); NT_ST(15, b7);

    // ---- epoch 2: prefetch group 3 into B; compute+store group 2 from A ----
    b0 = NT_LD(24); b1 = NT_LD(25); b2 = NT_LD(26); b3 = NT_LD(27);
    b4 = NT_LD(28); b5 = NT_LD(29); b6 = NT_LD(30); b7 = NT_LD(31);
    COMP(16, a0); COMP(17, a1); COMP(18, a2); COMP(19, a3);
    COMP(20, a4); COMP(21, a5); COMP(22, a6); COMP(23, a7);
    NT_ST(16, a0); NT_ST(17, a1); NT_ST(18, a2); NT_ST(19, a3);
    NT_ST(20, a4); NT_ST(21, a5); NT_ST(22, a6); NT_ST(23, a7);

    // ---- epoch 3: compute+store group 3 from B (no prefetch) ----
    COMP(24, b0); COMP(25, b1); COMP(26, b2); COMP(27, b3);
    COMP(28, b4); COMP(29, b5); COMP(30, b6); COMP(31, b7);
    NT_ST(24, b0); NT_ST(25, b1); NT_ST(26, b2); NT_ST(27, b3);
    NT_ST(28, b4); NT_ST(29, b5); NT_ST(30, b6); NT_ST(31, b7);

#undef COMP
#undef NT_ST
#undef NT_LD

    __builtin_nontemporal_store(mean, (f32x4*)(out_mean + pos));
    __builtin_nontemporal_store(m2,   (f32x4*)(out_m2   + pos));
    f32x4 nzf;
    nzf[0] = (float)nz[0]; nzf[1] = (float)nz[1];
    nzf[2] = (float)nz[2]; nzf[3] = (float)nz[3];
    __builtin_nontemporal_store(nzf,  (f32x4*)(out_nz   + pos));

    if (tid == 0) {
        out[(long long)(BATCH + 3) * SH] = (float)(n0 + BATCH);  // num_samples
    }
}

extern "C" void kernel_launch(void* const* d_in, const int* in_sizes, int n_in,
                              void* d_out, int out_size, void* d_ws, size_t ws_size,
                              hipStream_t stream) {
    const float* x    = (const float*)d_in[0];
    const float* mean = (const float*)d_in[1];
    const float* m2   = (const float*)d_in[2];
    const int*   nz   = (const int*)d_in[3];
    const int*   nsmp = (const int*)d_in[4];
    float* out = (float*)d_out;

    const long long n_threads = SH / 4;           // 524,288
    const int block = 256;
    const int grid = (int)((n_threads + block - 1) / block);  // 2048 blocks

    welford_kernel<<<grid, block, 0, stream>>>(x, mean, m2, nz, nsmp, out);
}